// Round 3
// baseline (55.742 us; speedup 1.0000x reference)
//
#include <hip/hip_runtime.h>

#define EPS_VAR 0.001f

__device__ __forceinline__ double wave_reduce(double v) {
    #pragma unroll
    for (int off = 32; off > 0; off >>= 1)
        v += __shfl_down(v, off, 64);
    return v;
}

// Fused kernel: each thread processes 2 consecutive valid indices,
// block-reduce -> partials in d_ws, last block (ticket atomic) finalizes.
__global__ __launch_bounds__(256) void rpn_fused(
    const float* __restrict__ pred,
    const float* __restrict__ unc,
    const float* __restrict__ cls,
    const float* __restrict__ gt,
    const int* __restrict__ lab,
    const int* __restrict__ vi,
    int V, int NB,
    double* __restrict__ part,          // [NB][5]
    unsigned int* __restrict__ ticket,  // zeroed by memsetAsync each call
    float* __restrict__ out) {

    double s_cls = 0.0, s_pos = 0.0, s_neg = 0.0;
    int n_pos = 0, n_neg = 0;

    const int base = blockIdx.x * 512 + threadIdx.x * 2;

    if (base + 1 < V) {
        // two consecutive sorted indices: int2 load, gathers usually share lines
        const int2 ii = *reinterpret_cast<const int2*>(vi + base);
        const int idx0 = ii.x, idx1 = ii.y;

        // issue all independent gathers up front (7 outstanding loads)
        const float2 lg0 = *reinterpret_cast<const float2*>(cls + 2ll * idx0);
        const float2 lg1 = *reinterpret_cast<const float2*>(cls + 2ll * idx1);
        const float4 u0  = *reinterpret_cast<const float4*>(unc + 4ll * idx0);
        const float4 u1  = *reinterpret_cast<const float4*>(unc + 4ll * idx1);
        const int l0 = lab[idx0];
        const int l1 = lab[idx1];

        // ---- elem 0 ----
        {
            const float mx = fmaxf(lg0.x, lg0.y);
            const float dd = fabsf(lg0.x - lg0.y);
            const float lse = mx + __logf(1.0f + __expf(-dd));
            s_cls += (double)(lse - ((l0 == 1) ? lg0.y : lg0.x));

            const float v0 = EPS_VAR + u0.x * u0.x;
            const float v1 = EPS_VAR + u0.y * u0.y;
            const float v2 = EPS_VAR + u0.z * u0.z;
            const float v3 = EPS_VAR + u0.w * u0.w;
            if (l0 == 1) {
                const float4 p = *reinterpret_cast<const float4*>(pred + 4ll * idx0);
                const float4 g = *reinterpret_cast<const float4*>(gt + 4ll * idx0);
                const float d0 = p.x - g.x, d1 = p.y - g.y;
                const float d2 = p.z - g.z, d3 = p.w - g.w;
                s_pos += (double)(0.5f * (d0 * d0 / v0 + d1 * d1 / v1 +
                                          d2 * d2 / v2 + d3 * d3 / v3)
                                  + 0.5f * __logf(v0 * v1 * v2 * v3));
                n_pos++;
            } else {
                s_neg += (double)(1.0f / v0 + 1.0f / v1 + 1.0f / v2 + 1.0f / v3);
                n_neg++;
            }
        }
        // ---- elem 1 ----
        {
            const float mx = fmaxf(lg1.x, lg1.y);
            const float dd = fabsf(lg1.x - lg1.y);
            const float lse = mx + __logf(1.0f + __expf(-dd));
            s_cls += (double)(lse - ((l1 == 1) ? lg1.y : lg1.x));

            const float v0 = EPS_VAR + u1.x * u1.x;
            const float v1 = EPS_VAR + u1.y * u1.y;
            const float v2 = EPS_VAR + u1.z * u1.z;
            const float v3 = EPS_VAR + u1.w * u1.w;
            if (l1 == 1) {
                const float4 p = *reinterpret_cast<const float4*>(pred + 4ll * idx1);
                const float4 g = *reinterpret_cast<const float4*>(gt + 4ll * idx1);
                const float d0 = p.x - g.x, d1 = p.y - g.y;
                const float d2 = p.z - g.z, d3 = p.w - g.w;
                s_pos += (double)(0.5f * (d0 * d0 / v0 + d1 * d1 / v1 +
                                          d2 * d2 / v2 + d3 * d3 / v3)
                                  + 0.5f * __logf(v0 * v1 * v2 * v3));
                n_pos++;
            } else {
                s_neg += (double)(1.0f / v0 + 1.0f / v1 + 1.0f / v2 + 1.0f / v3);
                n_neg++;
            }
        }
    } else {
        // tail: handle 0 or 1 remaining element scalar
        for (int i = base; i < V && i < base + 2; ++i) {
            const int idx = vi[i];
            const float2 lg = *reinterpret_cast<const float2*>(cls + 2ll * idx);
            const float4 u  = *reinterpret_cast<const float4*>(unc + 4ll * idx);
            const int l = lab[idx];
            const float mx = fmaxf(lg.x, lg.y);
            const float dd = fabsf(lg.x - lg.y);
            const float lse = mx + __logf(1.0f + __expf(-dd));
            s_cls += (double)(lse - ((l == 1) ? lg.y : lg.x));
            const float v0 = EPS_VAR + u.x * u.x;
            const float v1 = EPS_VAR + u.y * u.y;
            const float v2 = EPS_VAR + u.z * u.z;
            const float v3 = EPS_VAR + u.w * u.w;
            if (l == 1) {
                const float4 p = *reinterpret_cast<const float4*>(pred + 4ll * idx);
                const float4 g = *reinterpret_cast<const float4*>(gt + 4ll * idx);
                const float d0 = p.x - g.x, d1 = p.y - g.y;
                const float d2 = p.z - g.z, d3 = p.w - g.w;
                s_pos += (double)(0.5f * (d0 * d0 / v0 + d1 * d1 / v1 +
                                          d2 * d2 / v2 + d3 * d3 / v3)
                                  + 0.5f * __logf(v0 * v1 * v2 * v3));
                n_pos++;
            } else {
                s_neg += (double)(1.0f / v0 + 1.0f / v1 + 1.0f / v2 + 1.0f / v3);
                n_neg++;
            }
        }
    }

    // ---- block reduction ----
    __shared__ double sh[4][5];
    double r0 = wave_reduce(s_cls);
    double r1 = wave_reduce(s_pos);
    double r2 = wave_reduce(s_neg);
    double r3 = wave_reduce((double)n_pos);
    double r4 = wave_reduce((double)n_neg);

    const int wave = threadIdx.x >> 6;
    if ((threadIdx.x & 63) == 0) {
        sh[wave][0] = r0; sh[wave][1] = r1; sh[wave][2] = r2;
        sh[wave][3] = r3; sh[wave][4] = r4;
    }
    __syncthreads();

    __shared__ int sh_last;
    if (threadIdx.x == 0) {
        double a0 = 0, a1 = 0, a2 = 0, a3 = 0, a4 = 0;
        #pragma unroll
        for (int w = 0; w < 4; ++w) {
            a0 += sh[w][0]; a1 += sh[w][1]; a2 += sh[w][2];
            a3 += sh[w][3]; a4 += sh[w][4];
        }
        double* o = part + 5ll * blockIdx.x;
        o[0] = a0; o[1] = a1; o[2] = a2; o[3] = a3; o[4] = a4;
        __threadfence();  // release partials device-wide
        const unsigned int t = atomicAdd(ticket, 1u);
        sh_last = (t == (unsigned int)(NB - 1)) ? 1 : 0;
    }
    __syncthreads();

    if (sh_last) {
        __threadfence();  // acquire: invalidate stale cached partials
        double a0 = 0, a1 = 0, a2 = 0, a3 = 0, a4 = 0;
        for (int i = threadIdx.x; i < NB; i += 256) {
            const double* p = part + 5ll * i;
            a0 += p[0]; a1 += p[1]; a2 += p[2]; a3 += p[3]; a4 += p[4];
        }
        a0 = wave_reduce(a0);
        a1 = wave_reduce(a1);
        a2 = wave_reduce(a2);
        a3 = wave_reduce(a3);
        a4 = wave_reduce(a4);
        __syncthreads();  // sh[] reuse
        if ((threadIdx.x & 63) == 0) {
            sh[wave][0] = a0; sh[wave][1] = a1; sh[wave][2] = a2;
            sh[wave][3] = a3; sh[wave][4] = a4;
        }
        __syncthreads();
        if (threadIdx.x == 0) {
            double t0 = 0, t1 = 0, t2 = 0, t3 = 0, t4 = 0;
            #pragma unroll
            for (int w = 0; w < 4; ++w) {
                t0 += sh[w][0]; t1 += sh[w][1]; t2 += sh[w][2];
                t3 += sh[w][3]; t4 += sh[w][4];
            }
            const double class_loss = t0 / (double)V;
            const double reg_loss = t1 / t3 + t2 / t4;
            out[0] = (float)(class_loss + reg_loss);
        }
    }
}

extern "C" void kernel_launch(void* const* d_in, const int* in_sizes, int n_in,
                              void* d_out, int out_size, void* d_ws, size_t ws_size,
                              hipStream_t stream) {
    const float* pred = (const float*)d_in[0];
    const float* unc  = (const float*)d_in[1];
    const float* cls  = (const float*)d_in[2];
    const float* gt   = (const float*)d_in[3];
    const int*   lab  = (const int*)d_in[4];
    const int*   vi   = (const int*)d_in[5];
    const int V = in_sizes[5];

    const int NB = (V + 511) / 512;  // 2 elems/thread, 256 thr/block

    // ws layout: [0..3] ticket, [64..] partials (NB*5 doubles)
    unsigned int* ticket = (unsigned int*)d_ws;
    double* part = (double*)((char*)d_ws + 64);

    hipMemsetAsync(ticket, 0, sizeof(unsigned int), stream);
    rpn_fused<<<NB, 256, 0, stream>>>(pred, unc, cls, gt, lab, vi, V, NB,
                                      part, ticket, (float*)d_out);
}

// Round 4
// 33.087 us; speedup vs baseline: 1.6847x; 1.6847x over previous
//
#include <hip/hip_runtime.h>

#define EPS_VAR 0.001f

__device__ __forceinline__ double wave_reduce(double v) {
    #pragma unroll
    for (int off = 32; off > 0; off >>= 1)
        v += __shfl_down(v, off, 64);
    return v;
}

// Branchless per-element accumulate: both pos and neg terms computed,
// selected by label. No divergent loads.
__device__ __forceinline__ void accum_elem(
    int l, float2 lg, float4 u, float4 p, float4 g,
    double& s_cls, double& s_pos, double& s_neg, int& n_pos) {
    const float mx = fmaxf(lg.x, lg.y);
    const float dd = fabsf(lg.x - lg.y);
    const float lse = mx + __logf(1.0f + __expf(-dd));
    const bool pos = (l == 1);
    s_cls += (double)(lse - (pos ? lg.y : lg.x));

    const float v0 = EPS_VAR + u.x * u.x;
    const float v1 = EPS_VAR + u.y * u.y;
    const float v2 = EPS_VAR + u.z * u.z;
    const float v3 = EPS_VAR + u.w * u.w;

    const float d0 = p.x - g.x, d1 = p.y - g.y;
    const float d2 = p.z - g.z, d3 = p.w - g.w;
    const float pos_t = 0.5f * (d0 * d0 / v0 + d1 * d1 / v1 +
                                d2 * d2 / v2 + d3 * d3 / v3)
                      + 0.5f * __logf(v0 * v1 * v2 * v3);
    const float neg_t = 1.0f / v0 + 1.0f / v1 + 1.0f / v2 + 1.0f / v3;

    s_pos += (double)(pos ? pos_t : 0.0f);
    s_neg += (double)(pos ? 0.0f : neg_t);
    n_pos += pos ? 1 : 0;
}

// Pass 1: 4 consecutive valid indices per thread, all gathers issued up front
// (sorted indices => line sharing / L1 hits), block reduce -> 4 doubles/block.
__global__ __launch_bounds__(256) void rpn_pass1(
    const float* __restrict__ pred,
    const float* __restrict__ unc,
    const float* __restrict__ cls,
    const float* __restrict__ gt,
    const int* __restrict__ lab,
    const int* __restrict__ vi,
    int V,
    double* __restrict__ out_part) {

    double s_cls = 0.0, s_pos = 0.0, s_neg = 0.0;
    int n_pos = 0;

    const int t = blockIdx.x * 256 + threadIdx.x;
    const int base = t * 4;

    if (base + 3 < V) {
        const int4 ii = *reinterpret_cast<const int4*>(vi + base);
        const int i0 = ii.x, i1 = ii.y, i2 = ii.z, i3 = ii.w;

        // issue ALL 20 gathers before any use — max memory-level parallelism
        const int l0 = lab[i0], l1 = lab[i1], l2 = lab[i2], l3 = lab[i3];
        const float2 a0 = *reinterpret_cast<const float2*>(cls + 2ll * i0);
        const float2 a1 = *reinterpret_cast<const float2*>(cls + 2ll * i1);
        const float2 a2 = *reinterpret_cast<const float2*>(cls + 2ll * i2);
        const float2 a3 = *reinterpret_cast<const float2*>(cls + 2ll * i3);
        const float4 u0 = *reinterpret_cast<const float4*>(unc + 4ll * i0);
        const float4 u1 = *reinterpret_cast<const float4*>(unc + 4ll * i1);
        const float4 u2 = *reinterpret_cast<const float4*>(unc + 4ll * i2);
        const float4 u3 = *reinterpret_cast<const float4*>(unc + 4ll * i3);
        const float4 p0 = *reinterpret_cast<const float4*>(pred + 4ll * i0);
        const float4 p1 = *reinterpret_cast<const float4*>(pred + 4ll * i1);
        const float4 p2 = *reinterpret_cast<const float4*>(pred + 4ll * i2);
        const float4 p3 = *reinterpret_cast<const float4*>(pred + 4ll * i3);
        const float4 g0 = *reinterpret_cast<const float4*>(gt + 4ll * i0);
        const float4 g1 = *reinterpret_cast<const float4*>(gt + 4ll * i1);
        const float4 g2 = *reinterpret_cast<const float4*>(gt + 4ll * i2);
        const float4 g3 = *reinterpret_cast<const float4*>(gt + 4ll * i3);

        accum_elem(l0, a0, u0, p0, g0, s_cls, s_pos, s_neg, n_pos);
        accum_elem(l1, a1, u1, p1, g1, s_cls, s_pos, s_neg, n_pos);
        accum_elem(l2, a2, u2, p2, g2, s_cls, s_pos, s_neg, n_pos);
        accum_elem(l3, a3, u3, p3, g3, s_cls, s_pos, s_neg, n_pos);
    } else {
        for (int i = base; i < V && i < base + 4; ++i) {
            const int idx = vi[i];
            const int l = lab[idx];
            const float2 a = *reinterpret_cast<const float2*>(cls + 2ll * idx);
            const float4 u = *reinterpret_cast<const float4*>(unc + 4ll * idx);
            const float4 p = *reinterpret_cast<const float4*>(pred + 4ll * idx);
            const float4 g = *reinterpret_cast<const float4*>(gt + 4ll * idx);
            accum_elem(l, a, u, p, g, s_cls, s_pos, s_neg, n_pos);
        }
    }

    // block reduction: wave shuffle then LDS across the 4 waves
    __shared__ double sh[4][4];
    const double r0 = wave_reduce(s_cls);
    const double r1 = wave_reduce(s_pos);
    const double r2 = wave_reduce(s_neg);
    const double r3 = wave_reduce((double)n_pos);

    const int wave = threadIdx.x >> 6;
    if ((threadIdx.x & 63) == 0) {
        sh[wave][0] = r0; sh[wave][1] = r1; sh[wave][2] = r2; sh[wave][3] = r3;
    }
    __syncthreads();
    if (threadIdx.x == 0) {
        double a0 = 0, a1 = 0, a2 = 0, a3 = 0;
        #pragma unroll
        for (int w = 0; w < 4; ++w) {
            a0 += sh[w][0]; a1 += sh[w][1]; a2 += sh[w][2]; a3 += sh[w][3];
        }
        double* o = out_part + 4ll * blockIdx.x;
        o[0] = a0; o[1] = a1; o[2] = a2; o[3] = a3;
    }
}

// Pass 2: one block reduces all per-block partials; n_neg = V - n_pos.
__global__ __launch_bounds__(256) void rpn_pass2(
    const double* __restrict__ part, int nb, int V, float* __restrict__ out) {

    double a0 = 0, a1 = 0, a2 = 0, a3 = 0;
    for (int i = threadIdx.x; i < nb; i += 256) {
        const double* p = part + 4ll * i;
        a0 += p[0]; a1 += p[1]; a2 += p[2]; a3 += p[3];
    }

    __shared__ double sh[4][4];
    a0 = wave_reduce(a0);
    a1 = wave_reduce(a1);
    a2 = wave_reduce(a2);
    a3 = wave_reduce(a3);

    const int wave = threadIdx.x >> 6;
    if ((threadIdx.x & 63) == 0) {
        sh[wave][0] = a0; sh[wave][1] = a1; sh[wave][2] = a2; sh[wave][3] = a3;
    }
    __syncthreads();
    if (threadIdx.x == 0) {
        double t0 = 0, t1 = 0, t2 = 0, t3 = 0;
        #pragma unroll
        for (int w = 0; w < 4; ++w) {
            t0 += sh[w][0]; t1 += sh[w][1]; t2 += sh[w][2]; t3 += sh[w][3];
        }
        const double class_loss = t0 / (double)V;
        const double reg_loss = t1 / t3 + t2 / ((double)V - t3);
        out[0] = (float)(class_loss + reg_loss);
    }
}

extern "C" void kernel_launch(void* const* d_in, const int* in_sizes, int n_in,
                              void* d_out, int out_size, void* d_ws, size_t ws_size,
                              hipStream_t stream) {
    const float* pred = (const float*)d_in[0];
    const float* unc  = (const float*)d_in[1];
    const float* cls  = (const float*)d_in[2];
    const float* gt   = (const float*)d_in[3];
    const int*   lab  = (const int*)d_in[4];
    const int*   vi   = (const int*)d_in[5];
    const int V = in_sizes[5];

    const int NB = (V + 1023) / 1024;  // 4 elems/thread, 256 thr/block
    double* part = (double*)d_ws;      // NB * 4 doubles

    rpn_pass1<<<NB, 256, 0, stream>>>(pred, unc, cls, gt, lab, vi, V, part);
    rpn_pass2<<<1, 256, 0, stream>>>(part, NB, V, (float*)d_out);
}